// Round 11
// baseline (228.352 us; speedup 1.0000x reference)
//
#include <hip/hip_runtime.h>
#include <hip/hip_bf16.h>
#include <math.h>

// Problem constants
#define B 4
#define L 2048
#define HID 896
#define NH 14
#define NKV 2
#define HD 64
#define GROUPS 7           // NH / NKV
#define QCOLS (NH * HD)    // 896
#define KCOLS (NKV * HD)   // 128
#define ROWS (B * L)       // 8192
#define QKVS 1152          // fused qkv row stride (896 q + 128 k + 128 v)

typedef __attribute__((ext_vector_type(8))) short bf16x8;
typedef __attribute__((ext_vector_type(4))) short bf16x4;
typedef __attribute__((ext_vector_type(4))) float f32x4;
typedef unsigned short ushort_t;
typedef unsigned int uint_t;

__device__ inline short f2bf(float f) {
  union { __hip_bfloat16 h; short s; } u;
  u.h = __float2bfloat16(f);
  return u.s;
}

__device__ inline uint_t pack2_bf16(float a, float b) {
  return (uint_t)(ushort_t)f2bf(a) | ((uint_t)(ushort_t)f2bf(b) << 16);
}

#if defined(__HIP_DEVICE_COMPILE__)
__device__ inline f32x4 mfma16(bf16x4 a, bf16x4 b, f32x4 c) {
  return __builtin_amdgcn_mfma_f32_16x16x16bf16_1k(a, b, c, 0, 0, 0);
}
#define EXP2(x) __builtin_amdgcn_exp2f(x)
#else
// host-pass stubs (never executed; keep the parser happy)
__device__ inline f32x4 mfma16(bf16x4 a, bf16x4 b, f32x4 c) { return c; }
#define EXP2(x) exp2f(x)
#endif

__device__ inline void gload_lds16(const void* g, void* l) {
  __builtin_amdgcn_global_load_lds(
      (const __attribute__((address_space(1))) unsigned int*)g,
      (__attribute__((address_space(3))) unsigned int*)l, 16, 0, 0);
}

// ---------------------------------------------------------------------------
// One merged prep kernel: bf16 casts of x/wq/wk/wv/wo + bias pack.
// ---------------------------------------------------------------------------
__device__ inline void cast8(const float* __restrict__ in,
                             short* __restrict__ out) {
  const float4* p = (const float4*)in;
  float4 a = p[0], b = p[1];
  short s[8];
  s[0] = f2bf(a.x); s[1] = f2bf(a.y); s[2] = f2bf(a.z); s[3] = f2bf(a.w);
  s[4] = f2bf(b.x); s[5] = f2bf(b.y); s[6] = f2bf(b.z); s[7] = f2bf(b.w);
  *(bf16x8*)out = *(bf16x8*)s;
}

#define NX8 (ROWS * HID / 8)    // 917504
#define NQ8 (QCOLS * HID / 8)   // 100352
#define NK8 (KCOLS * HID / 8)   // 14336
#define PREP_TOTAL (NX8 + NQ8 + NK8 + NK8 + NQ8 + QKVS)

__global__ void prep_kernel(const float* __restrict__ x,
                            const float* __restrict__ wq,
                            const float* __restrict__ wk,
                            const float* __restrict__ wv,
                            const float* __restrict__ wo,
                            const float* __restrict__ bq,
                            const float* __restrict__ bk,
                            const float* __restrict__ bv,
                            short* __restrict__ xb,
                            short* __restrict__ wqkvb,
                            short* __restrict__ wob,
                            float* __restrict__ bqkv) {
  int i = blockIdx.x * blockDim.x + threadIdx.x;
  if (i < NX8) { cast8(x + (size_t)i * 8, xb + (size_t)i * 8); return; }
  i -= NX8;
  if (i < NQ8) { cast8(wq + (size_t)i * 8, wqkvb + (size_t)i * 8); return; }
  i -= NQ8;
  if (i < NK8) {
    cast8(wk + (size_t)i * 8, wqkvb + (size_t)QCOLS * HID + (size_t)i * 8);
    return;
  }
  i -= NK8;
  if (i < NK8) {
    cast8(wv + (size_t)i * 8,
          wqkvb + (size_t)(QCOLS + KCOLS) * HID + (size_t)i * 8);
    return;
  }
  i -= NK8;
  if (i < NQ8) { cast8(wo + (size_t)i * 8, wob + (size_t)i * 8); return; }
  i -= NQ8;
  if (i < QKVS) {
    float v;
    if (i < QCOLS) v = bq[i];
    else if (i < QCOLS + KCOLS) v = bk[i - QCOLS];
    else v = bv[i - QCOLS - KCOLS];
    bqkv[i] = v;
  }
}

// ---------------------------------------------------------------------------
// bf16 MFMA GEMM: C[M,N] = A[M,K] @ W[N,K]^T (+ bias).
// ROPE=true: bf16 out with fused RoPE (+QSCALE on q heads); else fp32 out.
// Wave's 64 output cols = exactly one 64-wide head (tiles 128, heads 64).
// r10: T1 XCD-chunked block swizzle (kept, +6us): vid=(o%8)*(nwg/8)+o/8.
// r11: GTK 32 -> 64. Barrier-drain frequency halves (28 -> 14 per block);
// each __syncthreads' implicit vmcnt(0) exposes load latency the short
// MFMA window can't cover (r7 showed counted-vmcnt can't fix it in this
// structure). LDS doubles to 64 KB but the grid already caps us at ~2
// blocks/CU, so no occupancy loss (m132's BK regression was an occupancy
// cut — rule 23, different regime).
// LDS layout: row-major [128][64]; granule g (8 shorts) of row r stored at
// position g^(r&7) via pre-swizzled gload SOURCE (rule 21). Read granule
// (4*kk+quad)^(l15&7): wave covers all 32 banks, 2 lanes/granule at
// distinct addresses = free (m136). Staging algebra: thread tid, instr j
// -> row = j*32 + (tid>>3), pos = tid&7, src granule = pos^(row&7) =
// (tid&7)^((tid>>3)&7) (j*32 mod 8 = 0) -> one base ptr + j*32*K offsets.
// Structure ledger: r6 2ph=best; r7 vmcnt-3buf -4.5; r8 1-wave -31.
// ---------------------------------------------------------------------------
#define GTM 128
#define GTN 128
#define GTK 64
#define QSCALE 0.18033688011112042f  // 0.125 * log2(e)

template <bool ROPE>
__global__ __launch_bounds__(256) void gemm_bf16_kernel(
    const short* __restrict__ A, const short* __restrict__ W,
    const float* __restrict__ bias, float* __restrict__ C,
    short* __restrict__ Cb, const float* __restrict__ cosp,
    const float* __restrict__ sinp, int M, int N, int K) {
  __shared__ short As[2][GTM * GTK];
  __shared__ short Bs[2][GTN * GTK];

  const int tid = threadIdx.x;
  const int wave = tid >> 6;
  const int lane = tid & 63;
  const int l15 = lane & 15;
  const int quad = lane >> 4;

  // XCD-chunked swizzle (r10): contiguous vid band per XCD -> A-panel L2 hit
  const int gx = gridDim.x;
  const int nwg = gx * gridDim.y;
  const int o = blockIdx.y * gx + blockIdx.x;
  const int vid = (o & 7) * (nwg >> 3) + (o >> 3);
  const int m0 = (vid / gx) * GTM;
  const int n0 = (vid % gx) * GTN;

  const int wm = (wave >> 1) * 64;
  const int wn = (wave & 1) * 64;

  f32x4 acc[4][4] = {};

  // staging: instr j covers rows j*32..j*32+31 (8 granules/row, 256 thr)
  const int srow = tid >> 3;
  const int sgl = (tid & 7) ^ (srow & 7);
  const short* Ag = A + (size_t)(m0 + srow) * K + sgl * 8;
  const short* Wg = W + (size_t)(n0 + srow) * K + sgl * 8;

  const int dl7 = l15 & 7;
  const int nsteps = K / GTK;

  auto stage = [&](int step, int bufi) {
    const int k0 = step * GTK;
#pragma unroll
    for (int j = 0; j < 4; ++j)
      gload_lds16(Ag + (size_t)j * 32 * K + k0, &As[bufi][j * 2048 + tid * 8]);
#pragma unroll
    for (int j = 0; j < 4; ++j)
      gload_lds16(Wg + (size_t)j * 32 * K + k0, &Bs[bufi][j * 2048 + tid * 8]);
  };

  stage(0, 0);
  __syncthreads();

  int cur = 0;
  for (int step = 0; step < nsteps; ++step) {
    if (step + 1 < nsteps) stage(step + 1, cur ^ 1);  // prefetch next tile

#pragma unroll
    for (int kk = 0; kk < 2; ++kk) {
      const int gof = ((4 * kk + quad) ^ dl7) * 8;
      bf16x8 af[4], bfr[4];
#pragma unroll
      for (int i = 0; i < 4; ++i)
        af[i] = *(bf16x8*)(&As[cur][(wm + i * 16 + l15) * GTK + gof]);
#pragma unroll
      for (int j = 0; j < 4; ++j)
        bfr[j] = *(bf16x8*)(&Bs[cur][(wn + j * 16 + l15) * GTK + gof]);
#pragma unroll
      for (int i = 0; i < 4; ++i)
#pragma unroll
        for (int j = 0; j < 4; ++j)
          acc[i][j] = __builtin_amdgcn_mfma_f32_16x16x32_bf16(
              af[i], bfr[j], acc[i][j], 0, 0, 0);
    }

    __syncthreads();  // prefetch landed + reads of cur done
    cur ^= 1;
  }

  const int col0 = n0 + wn + l15;
  if (ROPE) {
    const int hw = (n0 + wn) >> 6;  // head index within qkv row
    float bv[4];
#pragma unroll
    for (int j = 0; j < 4; ++j) bv[j] = bias[col0 + 16 * j];
    if (hw < NH + NKV) {
      // q/k head: rope pairs (d, d+32) = (j, j+2) in-register
      const float sc = (hw < NH) ? QSCALE : 1.0f;
#pragma unroll
      for (int i = 0; i < 4; ++i) {
        const int rowb = m0 + wm + i * 16 + quad * 4;
#pragma unroll
        for (int r = 0; r < 4; ++r) {
          const int row = rowb + r;
          const int l = row & (L - 1);
          const float* cp = cosp + l * HD + l15;
          const float* sp = sinp + l * HD + l15;
#pragma unroll
          for (int j = 0; j < 2; ++j) {
            const float cv = cp[16 * j];
            const float sv = sp[16 * j];
            const float a = acc[i][j][r] + bv[j];
            const float b2 = acc[i][j + 2][r] + bv[j + 2];
            Cb[(size_t)row * N + col0 + 16 * j] = f2bf((a * cv - b2 * sv) * sc);
            Cb[(size_t)row * N + col0 + 16 * j + 32] =
                f2bf((b2 * cv + a * sv) * sc);
          }
        }
      }
    } else {
      // v head: plain bias + bf16 store
#pragma unroll
      for (int j = 0; j < 4; ++j)
#pragma unroll
        for (int i = 0; i < 4; ++i) {
          const int rowb = m0 + wm + i * 16 + quad * 4;
#pragma unroll
          for (int r = 0; r < 4; ++r)
            Cb[(size_t)(rowb + r) * N + col0 + 16 * j] =
                f2bf(acc[i][j][r] + bv[j]);
        }
    }
  } else {
#pragma unroll
    for (int j = 0; j < 4; ++j) {
      const int col = col0 + 16 * j;
      const float bv = bias ? bias[col] : 0.f;
#pragma unroll
      for (int i = 0; i < 4; ++i) {
        const int rowb = m0 + wm + i * 16 + quad * 4;
#pragma unroll
        for (int r = 0; r < 4; ++r)
          C[(size_t)(rowb + r) * N + col] = acc[i][j][r] + bv;
      }
    }
  }
}

// ---------------------------------------------------------------------------
// Flash attention, S^T formulation. 512-thread blocks: 8 waves share ONE
// 128-row q-strip (16 q rows/wave) and ONE K/V LDS tile (BK=64 keys).
// __launch_bounds__(512, 4): 4 waves/SIMD = 2 blocks/CU. PINNED: HW VGPR
// granularity steps at {64,128,256} (m69); unified demand ~52 VGPR + ~24
// AGPR ~= 76 > 64, so any request >4 waves/SIMD forces the 64-reg step and
// spills (measured r1: (512,8) 2x slowdown; r9: (512,6) 78->126us,
// WRITE_SIZE 14->110 MB). Attn occupancy lever is CLOSED.
// Grid (56,16): y = GLOBAL strip rank (longest first); same-(h,b) blocks
// are 56 apart in dispatch order (56%8==0 -> same XCD -> KV L2-resident).
//   S^T[key][q] = mfma_16x16x32(A=K, B=Q)  (C: col=q=l15, row=key=quad*4+r)
//   C-layout == A/B-layout of mfma_16x16x16 -> PV with zero data movement:
//   O^T[d][q] += mfma_16x16x16(A=V^T-frag, B=P^T-frag).
// K and V^T tiles both XOR-granule-swizzled (8-short granule ^ row&7):
// all LDS ops are b128/b64, bank-conflict-free by construction.
// r3: ds_read_b64_tr_b16 V path corrupted output -> NOT used.
// r5: separate V-transpose kernel NEUTRAL -> reverted.
// Causal mask only on each wave's diagonal tile; defer-max (THR=8, log2
// domain) skips the O-rescale when no row max grows.
// ---------------------------------------------------------------------------
#define BK 64
#define QSTRIP 128
#define NSTRIPS (L / QSTRIP)  // 16

__global__ __launch_bounds__(512, 4) void attn_mfma_kernel(
    const ushort_t* __restrict__ qkv, ushort_t* __restrict__ ctx) {
  const int strip = (NSTRIPS - 1) - blockIdx.y;  // longest first
  const int h = blockIdx.x % NH;
  const int b = blockIdx.x / NH;
  const int kvh = h / GROUPS;
  const int tid = threadIdx.x;
  const int wave = tid >> 6;
  const int lane = tid & 63;
  const int l15 = lane & 15;
  const int quad = lane >> 4;

  const int lt = 2 * strip + 1;                 // block's last tile index
  const int qrb = strip * QSTRIP + wave * 16;   // this wave's q-row base
  const int myDiag = (qrb + 15) >> 6;           // wave's diagonal tile

  __shared__ short Kt[2][BK * 64];
  __shared__ short Vt[2][BK * 64];  // V^T: [d][key], granule-swizzled

  // Q fragments (QSCALE pre-folded by projection kernel)
  bf16x8 qf[2];
  {
    const ushort_t* qp = qkv + (size_t)(b * L + qrb + l15) * QKVS + h * HD;
    qf[0] = *(const bf16x8*)(qp + quad * 8);
    qf[1] = *(const bf16x8*)(qp + 32 + quad * 8);
  }

  float m = -INFINITY, lsum = 0.f;
  f32x4 o[4] = {};  // O^T: o[c][r] = O[q=l15][d=c*16+quad*4+r]

  const ushort_t* kb = qkv + (size_t)(b * L) * QKVS + QCOLS + kvh * HD;
  const ushort_t* vb = kb + KCOLS;

  // staging assignments (512 threads)
  const int skey = tid >> 3;                       // K: key row 0..63
  const int sgr = tid & 7;                         // K: granule 0..7
  const int ksw = skey * 64 + (sgr ^ (skey & 7)) * 8;
  const int vd = tid & 63;                         // V: d
  const int vsw = vd * 64 + ((wave ^ (vd & 7)) * 8);  // V: wave = key-granule

  uint4 kr, vrp;

  auto load_tile = [&](int j0) {
    kr = *(const uint4*)(kb + (size_t)(j0 + skey) * QKVS + sgr * 8);
    const ushort_t* vp = vb + (size_t)(j0 + wave * 8) * QKVS + vd;
    ushort_t vr[8];
#pragma unroll
    for (int s2 = 0; s2 < 8; ++s2) vr[s2] = vp[(size_t)s2 * QKVS];
    vrp.x = (uint_t)vr[0] | ((uint_t)vr[1] << 16);
    vrp.y = (uint_t)vr[2] | ((uint_t)vr[3] << 16);
    vrp.z = (uint_t)vr[4] | ((uint_t)vr[5] << 16);
    vrp.w = (uint_t)vr[6] | ((uint_t)vr[7] << 16);
  };
  auto store_tile = [&](int bufi) {
    *(uint4*)(&Kt[bufi][ksw]) = kr;
    *(uint4*)(&Vt[bufi][vsw]) = vrp;
  };

  load_tile(0);
  store_tile(0);
  __syncthreads();

  const int dl7 = l15 & 7;
  const int qh = quad >> 1;
  const int qoff = (quad & 1) * 4;

  for (int t = 0; t <= lt; ++t) {
    const int j0 = t * BK;
    const int cur = t & 1;
    if (t < lt) load_tile(j0 + BK);

    if (t <= myDiag) {  // wave-uniform: skip fully-masked tiles
      const short* Kb = Kt[cur];
      const short* Vb = Vt[cur];

      // ---- S^T = K Q^T (4 key-subtiles x 2 d-halves) ----
      f32x4 St[4];
      __builtin_amdgcn_s_setprio(1);
#pragma unroll
      for (int tt = 0; tt < 4; ++tt) {
        const int key = tt * 16 + l15;
        const short* krow = Kb + key * 64;
        bf16x8 k0 = *(const bf16x8*)(krow + (quad ^ (key & 7)) * 8);
        bf16x8 k1 = *(const bf16x8*)(krow + ((4 + quad) ^ (key & 7)) * 8);
        f32x4 a = {};
        a = __builtin_amdgcn_mfma_f32_16x16x32_bf16(k0, qf[0], a, 0, 0, 0);
        a = __builtin_amdgcn_mfma_f32_16x16x32_bf16(k1, qf[1], a, 0, 0, 0);
        St[tt] = a;
      }
      __builtin_amdgcn_s_setprio(0);

      // ---- causal mask only on the diagonal tile ----
      float s[16];
      if (t == myDiag) {
        const int limq = qrb + l15 - j0 - quad * 4;
#pragma unroll
        for (int tt = 0; tt < 4; ++tt)
#pragma unroll
          for (int r = 0; r < 4; ++r)
            s[tt * 4 + r] = (tt * 16 + r <= limq) ? St[tt][r] : -1e30f;
      } else {
#pragma unroll
        for (int tt = 0; tt < 4; ++tt)
#pragma unroll
          for (int r = 0; r < 4; ++r) s[tt * 4 + r] = St[tt][r];
      }

      // ---- online softmax (local-max exp trick + defer-max) ----
      float mt = fmaxf(s[0], s[1]);
#pragma unroll
      for (int i = 2; i < 16; ++i) mt = fmaxf(mt, s[i]);
      float pl[16], psl = 0.f;
#pragma unroll
      for (int i = 0; i < 16; ++i) {
        pl[i] = EXP2(s[i] - mt);
        psl += pl[i];
      }
      float mg = fmaxf(mt, __shfl_xor(mt, 16));
      mg = fmaxf(mg, __shfl_xor(mg, 32));

      float f;
      if (__all(mg <= m + 8.0f)) {
        // no (significant) new max: keep stale m, skip O-rescale
        f = EXP2(mt - m);
        lsum += psl * f;
      } else {
        const float mn = fmaxf(m, mg);
        const float al = EXP2(m - mn);
        f = EXP2(mt - mn);
        m = mn;
        lsum = lsum * al + psl * f;
#pragma unroll
        for (int c = 0; c < 4; ++c)
#pragma unroll
          for (int r = 0; r < 4; ++r) o[c][r] *= al;
      }

      uint_t pk[8];
#pragma unroll
      for (int tt = 0; tt < 4; ++tt) {
        pk[2 * tt] = pack2_bf16(pl[4 * tt] * f, pl[4 * tt + 1] * f);
        pk[2 * tt + 1] = pack2_bf16(pl[4 * tt + 2] * f, pl[4 * tt + 3] * f);
      }

      // ---- PV: O^T += V^T P^T (conflict-free b64 V reads) ----
      __builtin_amdgcn_s_setprio(1);
#pragma unroll
      for (int c = 0; c < 4; ++c) {
        const short* vrow = Vb + (c * 16 + l15) * 64;
#pragma unroll
        for (int tt = 0; tt < 4; ++tt) {
          const int g = tt * 2 + qh;
          union { bf16x4 v; uint2 u; } vfu;
          vfu.u = *(const uint2*)(vrow + ((g ^ dl7) * 8) + qoff);
          union { bf16x4 v; uint_t u[2]; } pa;
          pa.u[0] = pk[2 * tt];
          pa.u[1] = pk[2 * tt + 1];
          o[c] = mfma16(vfu.v, pa.v, o[c]);
        }
      }
      __builtin_amdgcn_s_setprio(0);
    }

    if (t < lt) store_tile(cur ^ 1);
    __syncthreads();
  }

  // ---- epilogue: reduce l across quads, normalize, bf16 store ----
  float s1 = lsum;
  s1 += __shfl_xor(s1, 16);
  s1 += __shfl_xor(s1, 32);
  const float inv = 1.0f / s1;
  ushort_t* cb = ctx + (size_t)(b * L) * QCOLS + h * HD;
#pragma unroll
  for (int c = 0; c < 4; ++c) {
    uint_t w[2];
    w[0] = pack2_bf16(o[c][0] * inv, o[c][1] * inv);
    w[1] = pack2_bf16(o[c][2] * inv, o[c][3] * inv);
    *(uint2*)(cb + (size_t)(qrb + l15) * QCOLS + c * 16 + quad * 4) =
        *(uint2*)w;
  }
}

// ---------------------------------------------------------------------------
extern "C" void kernel_launch(void* const* d_in, const int* in_sizes, int n_in,
                              void* d_out, int out_size, void* d_ws,
                              size_t ws_size, hipStream_t stream) {
  const float* x = (const float*)d_in[0];
  const float* cosp = (const float*)d_in[1];
  const float* sinp = (const float*)d_in[2];
  // d_in[3] = mask (unused)
  const float* wq = (const float*)d_in[4];
  const float* bq = (const float*)d_in[5];
  const float* wk = (const float*)d_in[6];
  const float* bk = (const float*)d_in[7];
  const float* wv = (const float*)d_in[8];
  const float* bv = (const float*)d_in[9];
  const float* wo = (const float*)d_in[10];
  float* out = (float*)d_out;

  char* ws = (char*)d_ws;
  ushort_t* qkvb = (ushort_t*)ws;  // [ROWS][QKVS] bf16, roped + q-scaled
  ws += (size_t)ROWS * QKVS * 2;
  short* xb = (short*)ws;
  ws += (size_t)ROWS * HID * 2;
  short* wqkvb = (short*)ws;
  ws += (size_t)QKVS * HID * 2;
  short* wob = (short*)ws;
  ws += (size_t)HID * QCOLS * 2;
  ushort_t* ctxb = (ushort_t*)ws;
  ws += (size_t)ROWS * QCOLS * 2;
  float* bqkv = (float*)ws;
  ws += QKVS * 4;

  // merged prep: casts + bias pack
  prep_kernel<<<(PREP_TOTAL + 255) / 256, 256, 0, stream>>>(
      x, wq, wk, wv, wo, bq, bk, bv, xb, wqkvb, wob, bqkv);

  // fused QKV projection + bias + RoPE + q-scale -> bf16 qkv
  gemm_bf16_kernel<true><<<dim3(QKVS / GTN, ROWS / GTM), 256, 0, stream>>>(
      xb, wqkvb, bqkv, nullptr, (short*)qkvb, cosp, sinp, ROWS, QKVS, HID);

  // attention -> bf16 ctx (512 threads; global longest-first strip order)
  attn_mfma_kernel<<<dim3(NH * B, NSTRIPS), 512, 0, stream>>>(qkvb, ctxb);

  // output projection -> fp32 out
  gemm_bf16_kernel<false><<<dim3(HID / GTN, ROWS / GTM), 256, 0, stream>>>(
      (const short*)ctxb, wob, nullptr, out, nullptr, nullptr, nullptr, ROWS,
      HID, QCOLS);
}

// Round 13
// 221.066 us; speedup vs baseline: 1.0330x; 1.0330x over previous
//
#include <hip/hip_runtime.h>
#include <hip/hip_bf16.h>
#include <math.h>

// Problem constants
#define B 4
#define L 2048
#define HID 896
#define NH 14
#define NKV 2
#define HD 64
#define GROUPS 7           // NH / NKV
#define QCOLS (NH * HD)    // 896
#define KCOLS (NKV * HD)   // 128
#define ROWS (B * L)       // 8192
#define QKVS 1152          // fused qkv row stride (896 q + 128 k + 128 v)

typedef __attribute__((ext_vector_type(8))) short bf16x8;
typedef __attribute__((ext_vector_type(4))) short bf16x4;
typedef __attribute__((ext_vector_type(4))) float f32x4;
typedef unsigned short ushort_t;
typedef unsigned int uint_t;

__device__ inline short f2bf(float f) {
  union { __hip_bfloat16 h; short s; } u;
  u.h = __float2bfloat16(f);
  return u.s;
}

__device__ inline uint_t pack2_bf16(float a, float b) {
  return (uint_t)(ushort_t)f2bf(a) | ((uint_t)(ushort_t)f2bf(b) << 16);
}

#if defined(__HIP_DEVICE_COMPILE__)
__device__ inline f32x4 mfma16(bf16x4 a, bf16x4 b, f32x4 c) {
  return __builtin_amdgcn_mfma_f32_16x16x16bf16_1k(a, b, c, 0, 0, 0);
}
#define EXP2(x) __builtin_amdgcn_exp2f(x)
#else
// host-pass stubs (never executed; keep the parser happy)
__device__ inline f32x4 mfma16(bf16x4 a, bf16x4 b, f32x4 c) { return c; }
#define EXP2(x) exp2f(x)
#endif

__device__ inline void gload_lds16(const void* g, void* l) {
  __builtin_amdgcn_global_load_lds(
      (const __attribute__((address_space(1))) unsigned int*)g,
      (__attribute__((address_space(3))) unsigned int*)l, 16, 0, 0);
}

// ---------------------------------------------------------------------------
// One merged prep kernel: bf16 casts of x/wq/wk/wv/wo + bias pack.
// ---------------------------------------------------------------------------
__device__ inline void cast8(const float* __restrict__ in,
                             short* __restrict__ out) {
  const float4* p = (const float4*)in;
  float4 a = p[0], b = p[1];
  short s[8];
  s[0] = f2bf(a.x); s[1] = f2bf(a.y); s[2] = f2bf(a.z); s[3] = f2bf(a.w);
  s[4] = f2bf(b.x); s[5] = f2bf(b.y); s[6] = f2bf(b.z); s[7] = f2bf(b.w);
  *(bf16x8*)out = *(bf16x8*)s;
}

#define NX8 (ROWS * HID / 8)    // 917504
#define NQ8 (QCOLS * HID / 8)   // 100352
#define NK8 (KCOLS * HID / 8)   // 14336
#define PREP_TOTAL (NX8 + NQ8 + NK8 + NK8 + NQ8 + QKVS)

__global__ void prep_kernel(const float* __restrict__ x,
                            const float* __restrict__ wq,
                            const float* __restrict__ wk,
                            const float* __restrict__ wv,
                            const float* __restrict__ wo,
                            const float* __restrict__ bq,
                            const float* __restrict__ bk,
                            const float* __restrict__ bv,
                            short* __restrict__ xb,
                            short* __restrict__ wqkvb,
                            short* __restrict__ wob,
                            float* __restrict__ bqkv) {
  int i = blockIdx.x * blockDim.x + threadIdx.x;
  if (i < NX8) { cast8(x + (size_t)i * 8, xb + (size_t)i * 8); return; }
  i -= NX8;
  if (i < NQ8) { cast8(wq + (size_t)i * 8, wqkvb + (size_t)i * 8); return; }
  i -= NQ8;
  if (i < NK8) {
    cast8(wk + (size_t)i * 8, wqkvb + (size_t)QCOLS * HID + (size_t)i * 8);
    return;
  }
  i -= NK8;
  if (i < NK8) {
    cast8(wv + (size_t)i * 8,
          wqkvb + (size_t)(QCOLS + KCOLS) * HID + (size_t)i * 8);
    return;
  }
  i -= NK8;
  if (i < NQ8) { cast8(wo + (size_t)i * 8, wob + (size_t)i * 8); return; }
  i -= NQ8;
  if (i < QKVS) {
    float v;
    if (i < QCOLS) v = bq[i];
    else if (i < QCOLS + KCOLS) v = bk[i - QCOLS];
    else v = bv[i - QCOLS - KCOLS];
    bqkv[i] = v;
  }
}

// ---------------------------------------------------------------------------
// bf16 MFMA GEMM: C[M,N] = A[M,K] @ W[N,K]^T (+ bias).  (r10-verified build)
// ROPE=true: bf16 out with fused RoPE (+QSCALE on q heads); else fp32 out.
// Wave's 64 output cols = exactly one 64-wide head (tiles 128, heads 64).
// LDS granule-swizzle: logical 16B granule g of row r stored at position
// g ^ ((r>>1)&3) (applied via pre-swizzled gload_lds SOURCE, rule 21).
// 2-phase prefetch: double-buffered As/Bs; stage(k+1) issued BEFORE
// compute(k), one __syncthreads per K-step.
// T1 XCD-chunked swizzle (+6us): vid=(o%8)*(nwg/8)+o/8 (bijective,
// 576%8==448%8==0) -> each XCD gets 8 contiguous M-tiles x all N ->
// A-panel + W working set ~3.9 MB fits per-XCD L2.
// Structure ledger (total deltas): 2-phase +10; XCD-swz +6; counted-vmcnt
// 3buf -4.5 (r7); GTK=64 -4.8 (r11); 1-wave 64^2 -31 (r8). In-structure
// levers EXHAUSTED at ~233 TF (m102 shape-curve regime, 2.25 blk/CU).
// ---------------------------------------------------------------------------
#define GTM 128
#define GTN 128
#define GTK 32
#define QSCALE 0.18033688011112042f  // 0.125 * log2(e)

template <bool ROPE>
__global__ __launch_bounds__(256) void gemm_bf16_kernel(
    const short* __restrict__ A, const short* __restrict__ W,
    const float* __restrict__ bias, float* __restrict__ C,
    short* __restrict__ Cb, const float* __restrict__ cosp,
    const float* __restrict__ sinp, int M, int N, int K) {
  __shared__ short As[2][GTM * GTK];
  __shared__ short Bs[2][GTN * GTK];

  const int tid = threadIdx.x;
  const int wave = tid >> 6;
  const int lane = tid & 63;
  const int l15 = lane & 15;
  const int quad = lane >> 4;

  // XCD-chunked swizzle: contiguous vid band per XCD -> A-panel L2 hit
  const int gx = gridDim.x;
  const int nwg = gx * gridDim.y;
  const int o = blockIdx.y * gx + blockIdx.x;
  const int vid = (o & 7) * (nwg >> 3) + (o >> 3);
  const int m0 = (vid / gx) * GTM;
  const int n0 = (vid % gx) * GTN;

  const int wm = (wave >> 1) * 64;
  const int wn = (wave & 1) * 64;

  f32x4 acc[4][4] = {};

  const int c0 = tid, c1 = tid + 256;
  const int r0 = c0 >> 2, g0 = (c0 & 3) ^ ((r0 >> 1) & 3);
  const int r1 = c1 >> 2, g1 = (c1 & 3) ^ ((r1 >> 1) & 3);
  const short* Ag0 = A + (size_t)(m0 + r0) * K + g0 * 8;
  const short* Ag1 = A + (size_t)(m0 + r1) * K + g1 * 8;
  const short* Wg0 = W + (size_t)(n0 + r0) * K + g0 * 8;
  const short* Wg1 = W + (size_t)(n0 + r1) * K + g1 * 8;

  const int goff = ((quad ^ ((l15 >> 1) & 3)) * 8);  // swizzled read offset

  const int nsteps = K / GTK;

  auto stage = [&](int step, int bufi) {
    const int k0 = step * GTK;
    gload_lds16(Ag0 + k0, &As[bufi][c0 * 8]);
    gload_lds16(Ag1 + k0, &As[bufi][c1 * 8]);
    gload_lds16(Wg0 + k0, &Bs[bufi][c0 * 8]);
    gload_lds16(Wg1 + k0, &Bs[bufi][c1 * 8]);
  };

  stage(0, 0);
  __syncthreads();

  int cur = 0;
  for (int step = 0; step < nsteps; ++step) {
    if (step + 1 < nsteps) stage(step + 1, cur ^ 1);  // prefetch next tile

    bf16x8 af[4], bfr[4];
#pragma unroll
    for (int i = 0; i < 4; ++i)
      af[i] = *(bf16x8*)(&As[cur][(wm + i * 16 + l15) * GTK + goff]);
#pragma unroll
    for (int j = 0; j < 4; ++j)
      bfr[j] = *(bf16x8*)(&Bs[cur][(wn + j * 16 + l15) * GTK + goff]);
#pragma unroll
    for (int i = 0; i < 4; ++i)
#pragma unroll
      for (int j = 0; j < 4; ++j)
        acc[i][j] = __builtin_amdgcn_mfma_f32_16x16x32_bf16(af[i], bfr[j],
                                                            acc[i][j], 0, 0, 0);

    __syncthreads();  // prefetch landed + reads of cur done
    cur ^= 1;
  }

  const int col0 = n0 + wn + l15;
  if (ROPE) {
    const int hw = (n0 + wn) >> 6;  // head index within qkv row
    float bv[4];
#pragma unroll
    for (int j = 0; j < 4; ++j) bv[j] = bias[col0 + 16 * j];
    if (hw < NH + NKV) {
      // q/k head: rope pairs (d, d+32) = (j, j+2) in-register
      const float sc = (hw < NH) ? QSCALE : 1.0f;
#pragma unroll
      for (int i = 0; i < 4; ++i) {
        const int rowb = m0 + wm + i * 16 + quad * 4;
#pragma unroll
        for (int r = 0; r < 4; ++r) {
          const int row = rowb + r;
          const int l = row & (L - 1);
          const float* cp = cosp + l * HD + l15;
          const float* sp = sinp + l * HD + l15;
#pragma unroll
          for (int j = 0; j < 2; ++j) {
            const float cv = cp[16 * j];
            const float sv = sp[16 * j];
            const float a = acc[i][j][r] + bv[j];
            const float b2 = acc[i][j + 2][r] + bv[j + 2];
            Cb[(size_t)row * N + col0 + 16 * j] = f2bf((a * cv - b2 * sv) * sc);
            Cb[(size_t)row * N + col0 + 16 * j + 32] =
                f2bf((b2 * cv + a * sv) * sc);
          }
        }
      }
    } else {
      // v head: plain bias + bf16 store
#pragma unroll
      for (int j = 0; j < 4; ++j)
#pragma unroll
        for (int i = 0; i < 4; ++i) {
          const int rowb = m0 + wm + i * 16 + quad * 4;
#pragma unroll
          for (int r = 0; r < 4; ++r)
            Cb[(size_t)(rowb + r) * N + col0 + 16 * j] =
                f2bf(acc[i][j][r] + bv[j]);
        }
    }
  } else {
#pragma unroll
    for (int j = 0; j < 4; ++j) {
      const int col = col0 + 16 * j;
      const float bv = bias ? bias[col] : 0.f;
#pragma unroll
      for (int i = 0; i < 4; ++i) {
        const int rowb = m0 + wm + i * 16 + quad * 4;
#pragma unroll
        for (int r = 0; r < 4; ++r)
          C[(size_t)(rowb + r) * N + col] = acc[i][j][r] + bv;
      }
    }
  }
}

// ---------------------------------------------------------------------------
// Flash attention, S^T formulation. 512-thread blocks: 8 waves share ONE
// 128-row q-strip (16 q rows/wave) and ONE K/V LDS tile (BK=64 keys).
// __launch_bounds__(512, 4): PINNED (r1/r9: any higher request hits the
// 64-VGPR HW step < ~76 unified demand -> catastrophic spill).
// r12 post-mortem: speculative softmax (m=0 init, exp2-before-max) FLAKED
// the post-timing determinism check (first run passed, replay diverged) —
// unexplained schedule-sensitive marginality -> REVERTED to the r10/r11
// verified softmax (local-max exp + defer-max).
// r13 probe: s_setprio REMOVED. T5's prerequisite is wave phase-diversity
// (m191 attn +4-7% on independent 1-wave blocks); our 8 waves are
// barrier-locked at 2 blocks/CU = the m190 GEMM-lockstep regime where
// setprio measured NEGATIVE (-1.5%): boosting one wave starves its
// barrier-mates. Zero structural change; clean A/B vs r10's 77.0us.
// Grid (56,16): y = GLOBAL strip rank (longest first); same-(h,b) blocks
// are 56 apart in dispatch order (56%8==0 -> same XCD -> KV L2-resident).
//   S^T[key][q] = mfma_16x16x32(A=K, B=Q)  (C: col=q=l15, row=key=quad*4+r)
//   C-layout == A/B-layout of mfma_16x16x16 -> PV with zero data movement:
//   O^T[d][q] += mfma_16x16x16(A=V^T-frag, B=P^T-frag).
// K and V^T tiles both XOR-granule-swizzled (8-short granule ^ row&7):
// all LDS ops are b128/b64, bank-conflict-free by construction.
// r3: ds_read_b64_tr_b16 V path corrupted output -> NOT used.
// r5: separate V-transpose kernel NEUTRAL -> reverted.
// Causal mask only on each wave's diagonal tile; defer-max (THR=8, log2
// domain) skips the O-rescale when no row max grows.
// ---------------------------------------------------------------------------
#define BK 64
#define QSTRIP 128
#define NSTRIPS (L / QSTRIP)  // 16

__global__ __launch_bounds__(512, 4) void attn_mfma_kernel(
    const ushort_t* __restrict__ qkv, ushort_t* __restrict__ ctx) {
  const int strip = (NSTRIPS - 1) - blockIdx.y;  // longest first
  const int h = blockIdx.x % NH;
  const int b = blockIdx.x / NH;
  const int kvh = h / GROUPS;
  const int tid = threadIdx.x;
  const int wave = tid >> 6;
  const int lane = tid & 63;
  const int l15 = lane & 15;
  const int quad = lane >> 4;

  const int lt = 2 * strip + 1;                 // block's last tile index
  const int qrb = strip * QSTRIP + wave * 16;   // this wave's q-row base
  const int myDiag = (qrb + 15) >> 6;           // wave's diagonal tile

  __shared__ short Kt[2][BK * 64];
  __shared__ short Vt[2][BK * 64];  // V^T: [d][key], granule-swizzled

  // Q fragments (QSCALE pre-folded by projection kernel)
  bf16x8 qf[2];
  {
    const ushort_t* qp = qkv + (size_t)(b * L + qrb + l15) * QKVS + h * HD;
    qf[0] = *(const bf16x8*)(qp + quad * 8);
    qf[1] = *(const bf16x8*)(qp + 32 + quad * 8);
  }

  float m = -INFINITY, lsum = 0.f;
  f32x4 o[4] = {};  // O^T: o[c][r] = O[q=l15][d=c*16+quad*4+r]

  const ushort_t* kb = qkv + (size_t)(b * L) * QKVS + QCOLS + kvh * HD;
  const ushort_t* vb = kb + KCOLS;

  // staging assignments (512 threads)
  const int skey = tid >> 3;                       // K: key row 0..63
  const int sgr = tid & 7;                         // K: granule 0..7
  const int ksw = skey * 64 + (sgr ^ (skey & 7)) * 8;
  const int vd = tid & 63;                         // V: d
  const int vsw = vd * 64 + ((wave ^ (vd & 7)) * 8);  // V: wave = key-granule

  uint4 kr, vrp;

  auto load_tile = [&](int j0) {
    kr = *(const uint4*)(kb + (size_t)(j0 + skey) * QKVS + sgr * 8);
    const ushort_t* vp = vb + (size_t)(j0 + wave * 8) * QKVS + vd;
    ushort_t vr[8];
#pragma unroll
    for (int s2 = 0; s2 < 8; ++s2) vr[s2] = vp[(size_t)s2 * QKVS];
    vrp.x = (uint_t)vr[0] | ((uint_t)vr[1] << 16);
    vrp.y = (uint_t)vr[2] | ((uint_t)vr[3] << 16);
    vrp.z = (uint_t)vr[4] | ((uint_t)vr[5] << 16);
    vrp.w = (uint_t)vr[6] | ((uint_t)vr[7] << 16);
  };
  auto store_tile = [&](int bufi) {
    *(uint4*)(&Kt[bufi][ksw]) = kr;
    *(uint4*)(&Vt[bufi][vsw]) = vrp;
  };

  load_tile(0);
  store_tile(0);
  __syncthreads();

  const int dl7 = l15 & 7;
  const int qh = quad >> 1;
  const int qoff = (quad & 1) * 4;

  for (int t = 0; t <= lt; ++t) {
    const int j0 = t * BK;
    const int cur = t & 1;
    if (t < lt) load_tile(j0 + BK);

    if (t <= myDiag) {  // wave-uniform: skip fully-masked tiles
      const short* Kb = Kt[cur];
      const short* Vb = Vt[cur];

      // ---- S^T = K Q^T (4 key-subtiles x 2 d-halves) ----
      f32x4 St[4];
#pragma unroll
      for (int tt = 0; tt < 4; ++tt) {
        const int key = tt * 16 + l15;
        const short* krow = Kb + key * 64;
        bf16x8 k0 = *(const bf16x8*)(krow + (quad ^ (key & 7)) * 8);
        bf16x8 k1 = *(const bf16x8*)(krow + ((4 + quad) ^ (key & 7)) * 8);
        f32x4 a = {};
        a = __builtin_amdgcn_mfma_f32_16x16x32_bf16(k0, qf[0], a, 0, 0, 0);
        a = __builtin_amdgcn_mfma_f32_16x16x32_bf16(k1, qf[1], a, 0, 0, 0);
        St[tt] = a;
      }

      // ---- causal mask only on the diagonal tile ----
      float s[16];
      if (t == myDiag) {
        const int limq = qrb + l15 - j0 - quad * 4;
#pragma unroll
        for (int tt = 0; tt < 4; ++tt)
#pragma unroll
          for (int r = 0; r < 4; ++r)
            s[tt * 4 + r] = (tt * 16 + r <= limq) ? St[tt][r] : -1e30f;
      } else {
#pragma unroll
        for (int tt = 0; tt < 4; ++tt)
#pragma unroll
          for (int r = 0; r < 4; ++r) s[tt * 4 + r] = St[tt][r];
      }

      // ---- online softmax (local-max exp trick + defer-max) ----
      float mt = fmaxf(s[0], s[1]);
#pragma unroll
      for (int i = 2; i < 16; ++i) mt = fmaxf(mt, s[i]);
      float pl[16], psl = 0.f;
#pragma unroll
      for (int i = 0; i < 16; ++i) {
        pl[i] = EXP2(s[i] - mt);
        psl += pl[i];
      }
      float mg = fmaxf(mt, __shfl_xor(mt, 16));
      mg = fmaxf(mg, __shfl_xor(mg, 32));

      float f;
      if (__all(mg <= m + 8.0f)) {
        // no (significant) new max: keep stale m, skip O-rescale
        f = EXP2(mt - m);
        lsum += psl * f;
      } else {
        const float mn = fmaxf(m, mg);
        const float al = EXP2(m - mn);
        f = EXP2(mt - mn);
        m = mn;
        lsum = lsum * al + psl * f;
#pragma unroll
        for (int c = 0; c < 4; ++c)
#pragma unroll
          for (int r = 0; r < 4; ++r) o[c][r] *= al;
      }

      uint_t pk[8];
#pragma unroll
      for (int tt = 0; tt < 4; ++tt) {
        pk[2 * tt] = pack2_bf16(pl[4 * tt] * f, pl[4 * tt + 1] * f);
        pk[2 * tt + 1] = pack2_bf16(pl[4 * tt + 2] * f, pl[4 * tt + 3] * f);
      }

      // ---- PV: O^T += V^T P^T (conflict-free b64 V reads) ----
#pragma unroll
      for (int c = 0; c < 4; ++c) {
        const short* vrow = Vb + (c * 16 + l15) * 64;
#pragma unroll
        for (int tt = 0; tt < 4; ++tt) {
          const int g = tt * 2 + qh;
          union { bf16x4 v; uint2 u; } vfu;
          vfu.u = *(const uint2*)(vrow + ((g ^ dl7) * 8) + qoff);
          union { bf16x4 v; uint_t u[2]; } pa;
          pa.u[0] = pk[2 * tt];
          pa.u[1] = pk[2 * tt + 1];
          o[c] = mfma16(vfu.v, pa.v, o[c]);
        }
      }
    }

    if (t < lt) store_tile(cur ^ 1);
    __syncthreads();
  }

  // ---- epilogue: reduce l across quads, normalize, bf16 store ----
  float s1 = lsum;
  s1 += __shfl_xor(s1, 16);
  s1 += __shfl_xor(s1, 32);
  const float inv = 1.0f / s1;
  ushort_t* cb = ctx + (size_t)(b * L) * QCOLS + h * HD;
#pragma unroll
  for (int c = 0; c < 4; ++c) {
    uint_t w[2];
    w[0] = pack2_bf16(o[c][0] * inv, o[c][1] * inv);
    w[1] = pack2_bf16(o[c][2] * inv, o[c][3] * inv);
    *(uint2*)(cb + (size_t)(qrb + l15) * QCOLS + c * 16 + quad * 4) =
        *(uint2*)w;
  }
}

// ---------------------------------------------------------------------------
extern "C" void kernel_launch(void* const* d_in, const int* in_sizes, int n_in,
                              void* d_out, int out_size, void* d_ws,
                              size_t ws_size, hipStream_t stream) {
  const float* x = (const float*)d_in[0];
  const float* cosp = (const float*)d_in[1];
  const float* sinp = (const float*)d_in[2];
  // d_in[3] = mask (unused)
  const float* wq = (const float*)d_in[4];
  const float* bq = (const float*)d_in[5];
  const float* wk = (const float*)d_in[6];
  const float* bk = (const float*)d_in[7];
  const float* wv = (const float*)d_in[8];
  const float* bv = (const float*)d_in[9];
  const float* wo = (const float*)d_in[10];
  float* out = (float*)d_out;

  char* ws = (char*)d_ws;
  ushort_t* qkvb = (ushort_t*)ws;  // [ROWS][QKVS] bf16, roped + q-scaled
  ws += (size_t)ROWS * QKVS * 2;
  short* xb = (short*)ws;
  ws += (size_t)ROWS * HID * 2;
  short* wqkvb = (short*)ws;
  ws += (size_t)QKVS * HID * 2;
  short* wob = (short*)ws;
  ws += (size_t)HID * QCOLS * 2;
  ushort_t* ctxb = (ushort_t*)ws;
  ws += (size_t)ROWS * QCOLS * 2;
  float* bqkv = (float*)ws;
  ws += QKVS * 4;

  // merged prep: casts + bias pack
  prep_kernel<<<(PREP_TOTAL + 255) / 256, 256, 0, stream>>>(
      x, wq, wk, wv, wo, bq, bk, bv, xb, wqkvb, wob, bqkv);

  // fused QKV projection + bias + RoPE + q-scale -> bf16 qkv
  gemm_bf16_kernel<true><<<dim3(QKVS / GTN, ROWS / GTM), 256, 0, stream>>>(
      xb, wqkvb, bqkv, nullptr, (short*)qkvb, cosp, sinp, ROWS, QKVS, HID);

  // attention -> bf16 ctx (512 threads; global longest-first strip order)
  attn_mfma_kernel<<<dim3(NH * B, NSTRIPS), 512, 0, stream>>>(qkvb, ctxb);

  // output projection -> fp32 out
  gemm_bf16_kernel<false><<<dim3(HID / GTN, ROWS / GTM), 256, 0, stream>>>(
      (const short*)ctxb, wob, nullptr, out, nullptr, nullptr, nullptr, ROWS,
      HID, QCOLS);
}